// Round 1
// baseline (894.496 us; speedup 1.0000x reference)
//
#include <hip/hip_runtime.h>

#define NN 100000
#define FD 64
#define OUTF 2

// ---------------- utility kernels ----------------

__global__ void k_zero(float* __restrict__ p, int n) {
    int i = blockIdx.x * blockDim.x + threadIdx.x;
    if (i < n) p[i] = 0.f;
}

__global__ void k_copy4(const float4* __restrict__ s, float4* __restrict__ d, int n4) {
    int i = blockIdx.x * blockDim.x + threadIdx.x;
    int st = gridDim.x * blockDim.x;
    for (; i < n4; i += st) d[i] = s[i];
}

// ---------------- edge scatter (atomics) ----------------
// wave per edge: lane = feature. agg[dst] += x[src]
__global__ void k_scatter(const float* __restrict__ x, const int* __restrict__ ei,
                          float* __restrict__ agg, int E_) {
    int lane = threadIdx.x & 63;
    int wid = (blockIdx.x * blockDim.x + threadIdx.x) >> 6;
    int nw = (gridDim.x * blockDim.x) >> 6;
    for (long e = wid; e < E_; e += nw) {
        int s = ei[e];
        int d = ei[E_ + e];
        float v = x[(long)s * FD + lane];
        atomicAdd(&agg[(long)d * FD + lane], v);
    }
}

// scatter of bn-transformed values: agg[dst] += h[src]*scale[c] + shift[c]
__global__ void k_scatter_bn(const float* __restrict__ h, const int* __restrict__ ei,
                             const float* __restrict__ sc, const float* __restrict__ sh,
                             float* __restrict__ agg, int E_) {
    int lane = threadIdx.x & 63;
    float scl = sc[lane];
    float shf = sh[lane];
    int wid = (blockIdx.x * blockDim.x + threadIdx.x) >> 6;
    int nw = (gridDim.x * blockDim.x) >> 6;
    for (long e = wid; e < E_; e += nw) {
        int s = ei[e];
        int d = ei[E_ + e];
        float v = fmaf(h[(long)s * FD + lane], scl, shf);
        atomicAdd(&agg[(long)d * FD + lane], v);
    }
}

// ---------------- MLP kernels ----------------
// per-thread node row staged in LDS (stride 65: 2-way bank alias = free).
// weights read with wave-uniform indices -> scalar loads.
__global__ __launch_bounds__(256) void k_mlp64(
        const float* __restrict__ X,
        const float* __restrict__ Wa, const float* __restrict__ ba,
        const float* __restrict__ Wb, const float* __restrict__ bb,
        float* __restrict__ H) {
    __shared__ float row[256 * 65];
    int tid = threadIdx.x;
    long node = (long)blockIdx.x * 256 + tid;
    bool valid = node < NN;
    if (valid) {
        const float4* rp = (const float4*)(X + node * FD);
#pragma unroll
        for (int q = 0; q < 16; q++) {
            float4 v = rp[q];
            row[tid * 65 + 4 * q + 0] = v.x;
            row[tid * 65 + 4 * q + 1] = v.y;
            row[tid * 65 + 4 * q + 2] = v.z;
            row[tid * 65 + 4 * q + 3] = v.w;
        }
    }
    float acc[64];
#pragma unroll
    for (int j = 0; j < 64; j++) acc[j] = ba[j];
    for (int k = 0; k < 64; k++) {
        float xv = row[tid * 65 + k];
        const float* wr = Wa + k * 64;
#pragma unroll
        for (int j = 0; j < 64; j++) acc[j] = fmaf(xv, wr[j], acc[j]);
    }
#pragma unroll
    for (int j = 0; j < 64; j++) row[tid * 65 + j] = fmaxf(acc[j], 0.f);
#pragma unroll
    for (int j = 0; j < 64; j++) acc[j] = bb[j];
    for (int k = 0; k < 64; k++) {
        float xv = row[tid * 65 + k];
        const float* wr = Wb + k * 64;
#pragma unroll
        for (int j = 0; j < 64; j++) acc[j] = fmaf(xv, wr[j], acc[j]);
    }
    if (valid) {
        float4* op = (float4*)(H + node * FD);
#pragma unroll
        for (int q = 0; q < 16; q++) {
            float4 v;
            v.x = fmaxf(acc[4 * q + 0], 0.f);
            v.y = fmaxf(acc[4 * q + 1], 0.f);
            v.z = fmaxf(acc[4 * q + 2], 0.f);
            v.w = fmaxf(acc[4 * q + 3], 0.f);
            op[q] = v;
        }
    }
}

// conv5 MLP: 64 -> 64 (relu) -> 2 (relu), writes [N,2]
__global__ __launch_bounds__(256) void k_mlp_out(
        const float* __restrict__ X,
        const float* __restrict__ Wa, const float* __restrict__ ba,
        const float* __restrict__ Wb, const float* __restrict__ bb,
        float* __restrict__ O) {
    __shared__ float row[256 * 65];
    int tid = threadIdx.x;
    long node = (long)blockIdx.x * 256 + tid;
    bool valid = node < NN;
    if (valid) {
        const float4* rp = (const float4*)(X + node * FD);
#pragma unroll
        for (int q = 0; q < 16; q++) {
            float4 v = rp[q];
            row[tid * 65 + 4 * q + 0] = v.x;
            row[tid * 65 + 4 * q + 1] = v.y;
            row[tid * 65 + 4 * q + 2] = v.z;
            row[tid * 65 + 4 * q + 3] = v.w;
        }
    }
    float acc[64];
#pragma unroll
    for (int j = 0; j < 64; j++) acc[j] = ba[j];
    for (int k = 0; k < 64; k++) {
        float xv = row[tid * 65 + k];
        const float* wr = Wa + k * 64;
#pragma unroll
        for (int j = 0; j < 64; j++) acc[j] = fmaf(xv, wr[j], acc[j]);
    }
#pragma unroll
    for (int j = 0; j < 64; j++) row[tid * 65 + j] = fmaxf(acc[j], 0.f);
    float a0 = bb[0];
    float a1 = bb[1];
    for (int k = 0; k < 64; k++) {
        float xv = row[tid * 65 + k];
        a0 = fmaf(xv, Wb[k * 2 + 0], a0);
        a1 = fmaf(xv, Wb[k * 2 + 1], a1);
    }
    if (valid) {
        float2 v;
        v.x = fmaxf(a0, 0.f);
        v.y = fmaxf(a1, 0.f);
        ((float2*)O)[node] = v;
    }
}

// ---------------- batchnorm stats / finalize / apply ----------------

__global__ __launch_bounds__(256) void k_stats64(const float* __restrict__ h,
                                                 float* __restrict__ gsum,
                                                 float* __restrict__ gsq) {
    int col = threadIdx.x & 63;
    int sub = threadIdx.x >> 6;  // 0..3
    float s = 0.f, q = 0.f;
    for (long r = (long)blockIdx.x * 4 + sub; r < NN; r += (long)gridDim.x * 4) {
        float v = h[r * 64 + col];
        s += v;
        q += v * v;
    }
    __shared__ float ls[4][64];
    __shared__ float lq[4][64];
    ls[sub][col] = s;
    lq[sub][col] = q;
    __syncthreads();
    if (threadIdx.x < 64) {
        s = ls[0][col] + ls[1][col] + ls[2][col] + ls[3][col];
        q = lq[0][col] + lq[1][col] + lq[2][col] + lq[3][col];
        atomicAdd(&gsum[col], s);
        atomicAdd(&gsq[col], q);
    }
}

__global__ __launch_bounds__(256) void k_stats2(const float* __restrict__ o,
                                                float* __restrict__ gsum,
                                                float* __restrict__ gsq) {
    float s0 = 0.f, s1 = 0.f, q0 = 0.f, q1 = 0.f;
    int t = blockIdx.x * blockDim.x + threadIdx.x;
    int st = gridDim.x * blockDim.x;
    for (long r = t; r < NN; r += st) {
        float2 v = ((const float2*)o)[r];
        s0 += v.x; q0 += v.x * v.x;
        s1 += v.y; q1 += v.y * v.y;
    }
    __shared__ float red[256][4];
    red[threadIdx.x][0] = s0;
    red[threadIdx.x][1] = q0;
    red[threadIdx.x][2] = s1;
    red[threadIdx.x][3] = q1;
    __syncthreads();
    for (int off = 128; off > 0; off >>= 1) {
        if (threadIdx.x < off) {
#pragma unroll
            for (int c = 0; c < 4; c++) red[threadIdx.x][c] += red[threadIdx.x + off][c];
        }
        __syncthreads();
    }
    if (threadIdx.x == 0) {
        atomicAdd(&gsum[0], red[0][0]);
        atomicAdd(&gsq[0], red[0][1]);
        atomicAdd(&gsum[1], red[0][2]);
        atomicAdd(&gsq[1], red[0][3]);
    }
}

__global__ void k_bnfin(const float* __restrict__ gsum, const float* __restrict__ gsq,
                        const float* __restrict__ g, const float* __restrict__ be,
                        float* __restrict__ sc, float* __restrict__ sh, int C, float invN) {
    int c = threadIdx.x;
    if (c < C) {
        float mu = gsum[c] * invN;
        float var = gsq[c] * invN - mu * mu;
        float s = g[c] * rsqrtf(var + 1e-5f);
        sc[c] = s;
        sh[c] = fmaf(-mu, s, be[c]);
    }
}

// agg2 init: o[i] = bn(h1[i]) (vectorized over float4; col block = i&15)
__global__ void k_bn_copy(const float4* __restrict__ h, const float4* __restrict__ sc4,
                          const float4* __restrict__ sh4, float4* __restrict__ o, int n4) {
    int i = blockIdx.x * blockDim.x + threadIdx.x;
    int st = gridDim.x * blockDim.x;
    for (; i < n4; i += st) {
        float4 v = h[i];
        int c = i & 15;
        float4 s = sc4[c];
        float4 b = sh4[c];
        v.x = fmaf(v.x, s.x, b.x);
        v.y = fmaf(v.y, s.y, b.y);
        v.z = fmaf(v.z, s.z, b.z);
        v.w = fmaf(v.w, s.w, b.w);
        o[i] = v;
    }
}

// final BN apply in-place on d_out [N,2]
__global__ void k_bn_apply2(float* __restrict__ o, const float* __restrict__ sc,
                            const float* __restrict__ sh, int n) {
    int i = blockIdx.x * blockDim.x + threadIdx.x;
    if (i < n) {
        int c = i & 1;
        o[i] = fmaf(o[i], sc[c], sh[c]);
    }
}

// ---------------- launch ----------------

extern "C" void kernel_launch(void* const* d_in, const int* in_sizes, int n_in,
                              void* d_out, int out_size, void* d_ws, size_t ws_size,
                              hipStream_t stream) {
    const float* x   = (const float*)d_in[0];
    const int*   ei  = (const int*)d_in[1];
    const float* W1a = (const float*)d_in[2];
    const float* b1a = (const float*)d_in[3];
    const float* W1b = (const float*)d_in[4];
    const float* b1b = (const float*)d_in[5];
    const float* g1  = (const float*)d_in[6];
    const float* be1 = (const float*)d_in[7];
    const float* W5a = (const float*)d_in[8];
    const float* b5a = (const float*)d_in[9];
    const float* W5b = (const float*)d_in[10];
    const float* b5b = (const float*)d_in[11];
    const float* g5  = (const float*)d_in[12];
    const float* be5 = (const float*)d_in[13];
    float* out = (float*)d_out;

    const int E = in_sizes[1] / 2;

    float* ws = (float*)d_ws;
    float* agg = ws;                  // [N,64]  (agg1, later agg2)
    float* h1  = ws + (long)NN * FD;  // [N,64]
    float* S   = ws + 2L * NN * FD;   // stats & bn params
    float* gsum1  = S;        // 64
    float* gsq1   = S + 64;   // 64
    float* gsum2  = S + 128;  // 2
    float* gsq2   = S + 160;  // 2
    float* scale1 = S + 192;  // 64 (16B aligned)
    float* shift1 = S + 256;  // 64
    float* scale2 = S + 320;  // 2
    float* shift2 = S + 328;  // 2

    const int n4 = NN * FD / 4;  // 1.6M float4

    // zero stat accumulators (ws is poisoned 0xAA before every call)
    k_zero<<<1, 256, 0, stream>>>(S, 192);

    // conv1 aggregation: agg = x + scatter(x)
    k_copy4<<<4096, 256, 0, stream>>>((const float4*)x, (float4*)agg, n4);
    k_scatter<<<4096, 256, 0, stream>>>(x, ei, agg, E);

    // conv1 MLP -> h1
    k_mlp64<<<(NN + 255) / 256, 256, 0, stream>>>(agg, W1a, b1a, W1b, b1b, h1);

    // BN1 stats + finalize
    k_stats64<<<256, 256, 0, stream>>>(h1, gsum1, gsq1);
    k_bnfin<<<1, 64, 0, stream>>>(gsum1, gsq1, g1, be1, scale1, shift1, 64, 1.f / NN);

    // conv5 aggregation on bn(h1): agg = bn(h1) + scatter(bn(h1))
    k_bn_copy<<<4096, 256, 0, stream>>>((const float4*)h1, (const float4*)scale1,
                                        (const float4*)shift1, (float4*)agg, n4);
    k_scatter_bn<<<4096, 256, 0, stream>>>(h1, ei, scale1, shift1, agg, E);

    // conv5 MLP -> out [N,2]
    k_mlp_out<<<(NN + 255) / 256, 256, 0, stream>>>(agg, W5a, b5a, W5b, b5b, out);

    // BN2 stats + finalize + apply in-place
    k_stats2<<<256, 256, 0, stream>>>(out, gsum2, gsq2);
    k_bnfin<<<1, 64, 0, stream>>>(gsum2, gsq2, g5, be5, scale2, shift2, OUTF, 1.f / NN);
    k_bn_apply2<<<(NN * OUTF + 255) / 256, 256, 0, stream>>>(out, scale2, shift2, NN * OUTF);
}

// Round 3
// 597.796 us; speedup vs baseline: 1.4963x; 1.4963x over previous
//
#include <hip/hip_runtime.h>

#define NN 100000
#define FD 64
#define OUTF 2
#define CHUNK 1024
#define NCH 98  // ceil(NN/CHUNK)

// ---------------- utility kernels ----------------

__global__ void k_zero(float* __restrict__ p, int n) {
    int i = blockIdx.x * blockDim.x + threadIdx.x;
    if (i < n) p[i] = 0.f;
}

__global__ void k_zero2(int* __restrict__ a, int na, float* __restrict__ b, int nb) {
    int i = blockIdx.x * blockDim.x + threadIdx.x;
    if (i < na) a[i] = 0;
    if (i < nb) b[i] = 0.f;
}

__global__ void k_copy4(const float4* __restrict__ s, float4* __restrict__ d, int n4) {
    int i = blockIdx.x * blockDim.x + threadIdx.x;
    int st = gridDim.x * blockDim.x;
    for (; i < n4; i += st) d[i] = s[i];
}

// ---------------- CSR build ----------------

__global__ void k_hist(const int* __restrict__ ei, int* __restrict__ cnt, int E_) {
    int i = blockIdx.x * blockDim.x + threadIdx.x;
    int st = gridDim.x * blockDim.x;
    for (; i < E_; i += st) {
        int d = ei[E_ + i];
        d = min(max(d, 0), NN - 1);
        atomicAdd(&cnt[d], 1);
    }
}

__global__ __launch_bounds__(256) void k_scanA(const int4* __restrict__ cnt4,
                                               int* __restrict__ part,
                                               int* __restrict__ bsum) {
    __shared__ int ts[256];
    int blk = blockIdx.x, tid = threadIdx.x;
    int4 c = cnt4[blk * 256 + tid];
    int s = c.x + c.y + c.z + c.w;
    ts[tid] = s;
    __syncthreads();
    for (int off = 1; off < 256; off <<= 1) {
        int v = (tid >= off) ? ts[tid - off] : 0;
        __syncthreads();
        ts[tid] += v;
        __syncthreads();
    }
    int excl = ts[tid] - s;
    int base = blk * CHUNK + tid * 4;
    part[base + 0] = excl;
    part[base + 1] = excl + c.x;
    part[base + 2] = excl + c.x + c.y;
    part[base + 3] = excl + c.x + c.y + c.z;
    if (tid == 255) bsum[blk] = ts[255];
}

// NOTE: does NOT write rowptr[NN] — rowptr aliases the partial array that
// k_scanC still needs to read. k_scanC itself produces rowptr[NN] correctly
// (index NN < NCH*CHUNK is inside its coverage). Round-2 abort root cause.
__global__ void k_scanB(const int* __restrict__ bsum, int* __restrict__ boffs) {
    __shared__ int ts[128];
    int tid = threadIdx.x;
    int v = (tid < NCH) ? bsum[tid] : 0;
    ts[tid] = v;
    __syncthreads();
    for (int off = 1; off < 128; off <<= 1) {
        int u = (tid >= off) ? ts[tid - off] : 0;
        __syncthreads();
        ts[tid] += u;
        __syncthreads();
    }
    boffs[tid] = ts[tid] - v;
}

__global__ __launch_bounds__(256) void k_scanC(int* __restrict__ rowptr,
                                               const int* __restrict__ boffs,
                                               int* __restrict__ cur) {
    int blk = blockIdx.x, tid = threadIdx.x;
    int off = boffs[blk];
    int base = blk * CHUNK + tid * 4;
#pragma unroll
    for (int q = 0; q < 4; q++) {
        int i = base + q;
        int v = rowptr[i] + off;
        rowptr[i] = v;
        cur[i] = v;
    }
}

__global__ void k_fill(const int* __restrict__ ei, int* __restrict__ cur,
                       int* __restrict__ csr, int E_) {
    int i = blockIdx.x * blockDim.x + threadIdx.x;
    int st = gridDim.x * blockDim.x;
    for (; i < E_; i += st) {
        int s = ei[i];
        int d = ei[E_ + i];
        d = min(max(d, 0), NN - 1);
        int pos = atomicAdd(&cur[d], 1);
        pos = min(max(pos, 0), E_ - 1);  // insurance, never hit when scan correct
        csr[pos] = s;
    }
}

// ---------------- gather aggregation ----------------
// one wave per node, lane = feature. out[n] = X[n] + sum_{s in N(n)} X[s],
// optionally affine: out = sc[lane]*sum + (deg+1)*sh[lane]
__global__ __launch_bounds__(256) void k_gather(const float* __restrict__ X,
                                                const int* __restrict__ rowptr,
                                                const int* __restrict__ csr,
                                                const float* __restrict__ sc,
                                                const float* __restrict__ sh,
                                                float* __restrict__ out, int E_) {
    int lane = threadIdx.x & 63;
    int n = (blockIdx.x * blockDim.x + threadIdx.x) >> 6;
    if (n >= NN) return;
    int start = rowptr[n], end = rowptr[n + 1];
    // insurance clamps (no-ops when CSR build is correct)
    start = min(max(start, 0), E_);
    end = min(max(end, start), E_);
    float acc = X[(long)n * FD + lane];
    for (int base = start; base < end; base += 64) {
        int rem = end - base;
        int cnt = rem < 64 ? rem : 64;
        int id = 0;
        if (lane < cnt) id = min(max(csr[base + lane], 0), NN - 1);
        for (int j = 0; j < cnt; j++) {
            int s = __shfl(id, j);
            acc += X[(long)s * FD + lane];
        }
    }
    if (sc) {
        int deg = end - start;
        acc = fmaf(acc, sc[lane], (float)(deg + 1) * sh[lane]);
    }
    out[(long)n * FD + lane] = acc;
}

// ---------------- MLP kernels (BN stats fused into epilogue) ----------------

__global__ __launch_bounds__(256) void k_mlp64(
        const float* __restrict__ X,
        const float* __restrict__ Wa, const float* __restrict__ ba,
        const float* __restrict__ Wb, const float* __restrict__ bb,
        float* __restrict__ H, float* __restrict__ gsum, float* __restrict__ gsq) {
    __shared__ float row[256 * 65];
    int tid = threadIdx.x;
    long node = (long)blockIdx.x * 256 + tid;
    bool valid = node < NN;
    if (valid) {
        const float4* rp = (const float4*)(X + node * FD);
#pragma unroll
        for (int q = 0; q < 16; q++) {
            float4 v = rp[q];
            row[tid * 65 + 4 * q + 0] = v.x;
            row[tid * 65 + 4 * q + 1] = v.y;
            row[tid * 65 + 4 * q + 2] = v.z;
            row[tid * 65 + 4 * q + 3] = v.w;
        }
    }
    float acc[64];
#pragma unroll
    for (int j = 0; j < 64; j++) acc[j] = ba[j];
    if (valid) {
        for (int k = 0; k < 64; k++) {
            float xv = row[tid * 65 + k];
            const float* wr = Wa + k * 64;
#pragma unroll
            for (int j = 0; j < 64; j++) acc[j] = fmaf(xv, wr[j], acc[j]);
        }
    }
#pragma unroll
    for (int j = 0; j < 64; j++) row[tid * 65 + j] = fmaxf(acc[j], 0.f);
#pragma unroll
    for (int j = 0; j < 64; j++) acc[j] = bb[j];
    if (valid) {
        for (int k = 0; k < 64; k++) {
            float xv = row[tid * 65 + k];
            const float* wr = Wb + k * 64;
#pragma unroll
            for (int j = 0; j < 64; j++) acc[j] = fmaf(xv, wr[j], acc[j]);
        }
    }
    // final h (post-relu) back to LDS for stats; invalid rows contribute 0
#pragma unroll
    for (int j = 0; j < 64; j++) {
        float v = valid ? fmaxf(acc[j], 0.f) : 0.f;
        row[tid * 65 + j] = v;
    }
    if (valid) {
        float4* op = (float4*)(H + node * FD);
#pragma unroll
        for (int q = 0; q < 16; q++) {
            float4 v;
            v.x = row[tid * 65 + 4 * q + 0];
            v.y = row[tid * 65 + 4 * q + 1];
            v.z = row[tid * 65 + 4 * q + 2];
            v.w = row[tid * 65 + 4 * q + 3];
            op[q] = v;
        }
    }
    __syncthreads();
    if (tid < 64) {
        float s = 0.f, q = 0.f;
        for (int r = 0; r < 256; r++) {
            float v = row[r * 65 + tid];
            s += v;
            q += v * v;
        }
        atomicAdd(&gsum[tid], s);
        atomicAdd(&gsq[tid], q);
    }
}

__global__ __launch_bounds__(256) void k_mlp_out(
        const float* __restrict__ X,
        const float* __restrict__ Wa, const float* __restrict__ ba,
        const float* __restrict__ Wb, const float* __restrict__ bb,
        float* __restrict__ O, float* __restrict__ gsum, float* __restrict__ gsq) {
    __shared__ float row[256 * 65];
    __shared__ float red[256][4];
    int tid = threadIdx.x;
    long node = (long)blockIdx.x * 256 + tid;
    bool valid = node < NN;
    if (valid) {
        const float4* rp = (const float4*)(X + node * FD);
#pragma unroll
        for (int q = 0; q < 16; q++) {
            float4 v = rp[q];
            row[tid * 65 + 4 * q + 0] = v.x;
            row[tid * 65 + 4 * q + 1] = v.y;
            row[tid * 65 + 4 * q + 2] = v.z;
            row[tid * 65 + 4 * q + 3] = v.w;
        }
    }
    float acc[64];
#pragma unroll
    for (int j = 0; j < 64; j++) acc[j] = ba[j];
    if (valid) {
        for (int k = 0; k < 64; k++) {
            float xv = row[tid * 65 + k];
            const float* wr = Wa + k * 64;
#pragma unroll
            for (int j = 0; j < 64; j++) acc[j] = fmaf(xv, wr[j], acc[j]);
        }
    }
#pragma unroll
    for (int j = 0; j < 64; j++) row[tid * 65 + j] = fmaxf(acc[j], 0.f);
    float a0 = bb[0];
    float a1 = bb[1];
    if (valid) {
        for (int k = 0; k < 64; k++) {
            float xv = row[tid * 65 + k];
            a0 = fmaf(xv, Wb[k * 2 + 0], a0);
            a1 = fmaf(xv, Wb[k * 2 + 1], a1);
        }
    }
    float v0 = valid ? fmaxf(a0, 0.f) : 0.f;
    float v1 = valid ? fmaxf(a1, 0.f) : 0.f;
    if (valid) {
        float2 v;
        v.x = v0;
        v.y = v1;
        ((float2*)O)[node] = v;
    }
    red[tid][0] = v0;
    red[tid][1] = v0 * v0;
    red[tid][2] = v1;
    red[tid][3] = v1 * v1;
    __syncthreads();
    for (int off = 128; off > 0; off >>= 1) {
        if (tid < off) {
#pragma unroll
            for (int c = 0; c < 4; c++) red[tid][c] += red[tid + off][c];
        }
        __syncthreads();
    }
    if (tid == 0) {
        atomicAdd(&gsum[0], red[0][0]);
        atomicAdd(&gsq[0], red[0][1]);
        atomicAdd(&gsum[1], red[0][2]);
        atomicAdd(&gsq[1], red[0][3]);
    }
}

// ---------------- batchnorm finalize / apply ----------------

__global__ void k_bnfin(const float* __restrict__ gsum, const float* __restrict__ gsq,
                        const float* __restrict__ g, const float* __restrict__ be,
                        float* __restrict__ sc, float* __restrict__ sh, int C, float invN) {
    int c = threadIdx.x;
    if (c < C) {
        float mu = gsum[c] * invN;
        float var = gsq[c] * invN - mu * mu;
        float s = g[c] * rsqrtf(var + 1e-5f);
        sc[c] = s;
        sh[c] = fmaf(-mu, s, be[c]);
    }
}

__global__ void k_bn_apply2(float* __restrict__ o, const float* __restrict__ sc,
                            const float* __restrict__ sh, int n) {
    int i = blockIdx.x * blockDim.x + threadIdx.x;
    if (i < n) {
        int c = i & 1;
        o[i] = fmaf(o[i], sc[c], sh[c]);
    }
}

// ---------------- fallback (round-1) atomic scatter kernels ----------------

__global__ void k_scatter(const float* __restrict__ x, const int* __restrict__ ei,
                          float* __restrict__ agg, int E_) {
    int lane = threadIdx.x & 63;
    int wid = (blockIdx.x * blockDim.x + threadIdx.x) >> 6;
    int nw = (gridDim.x * blockDim.x) >> 6;
    for (long e = wid; e < E_; e += nw) {
        int s = ei[e];
        int d = ei[E_ + e];
        float v = x[(long)s * FD + lane];
        atomicAdd(&agg[(long)d * FD + lane], v);
    }
}

__global__ void k_scatter_bn(const float* __restrict__ h, const int* __restrict__ ei,
                             const float* __restrict__ sc, const float* __restrict__ sh,
                             float* __restrict__ agg, int E_) {
    int lane = threadIdx.x & 63;
    float scl = sc[lane];
    float shf = sh[lane];
    int wid = (blockIdx.x * blockDim.x + threadIdx.x) >> 6;
    int nw = (gridDim.x * blockDim.x) >> 6;
    for (long e = wid; e < E_; e += nw) {
        int s = ei[e];
        int d = ei[E_ + e];
        float v = fmaf(h[(long)s * FD + lane], scl, shf);
        atomicAdd(&agg[(long)d * FD + lane], v);
    }
}

__global__ void k_bn_copy(const float4* __restrict__ h, const float4* __restrict__ sc4,
                          const float4* __restrict__ sh4, float4* __restrict__ o, int n4) {
    int i = blockIdx.x * blockDim.x + threadIdx.x;
    int st = gridDim.x * blockDim.x;
    for (; i < n4; i += st) {
        float4 v = h[i];
        int c = i & 15;
        float4 s = sc4[c];
        float4 b = sh4[c];
        v.x = fmaf(v.x, s.x, b.x);
        v.y = fmaf(v.y, s.y, b.y);
        v.z = fmaf(v.z, s.z, b.z);
        v.w = fmaf(v.w, s.w, b.w);
        o[i] = v;
    }
}

// ---------------- launch ----------------

extern "C" void kernel_launch(void* const* d_in, const int* in_sizes, int n_in,
                              void* d_out, int out_size, void* d_ws, size_t ws_size,
                              hipStream_t stream) {
    const float* x   = (const float*)d_in[0];
    const int*   ei  = (const int*)d_in[1];
    const float* W1a = (const float*)d_in[2];
    const float* b1a = (const float*)d_in[3];
    const float* W1b = (const float*)d_in[4];
    const float* b1b = (const float*)d_in[5];
    const float* g1  = (const float*)d_in[6];
    const float* be1 = (const float*)d_in[7];
    const float* W5a = (const float*)d_in[8];
    const float* b5a = (const float*)d_in[9];
    const float* W5b = (const float*)d_in[10];
    const float* b5b = (const float*)d_in[11];
    const float* g5  = (const float*)d_in[12];
    const float* be5 = (const float*)d_in[13];
    float* out = (float*)d_out;

    const int E = in_sizes[1] / 2;

    float* ws = (float*)d_ws;
    float* agg = ws;                   // [N,64]
    float* h1  = ws + (long)NN * FD;   // [N,64]
    float* S   = ws + 2L * NN * FD;    // 512 floats: stats & bn params
    float* gsum1  = S;        // 64
    float* gsq1   = S + 64;   // 64
    float* gsum2  = S + 128;  // 2
    float* gsq2   = S + 160;  // 2
    float* scale1 = S + 192;  // 64
    float* shift1 = S + 256;  // 64
    float* scale2 = S + 320;  // 2
    float* shift2 = S + 328;  // 2

    // int region (16B-aligned offset)
    int* ibase  = (int*)(S + 512);
    int* rowptr = ibase;            // NCH*CHUNK + 4 = 100356
    int* cnt    = ibase + 100356;   // NCH*CHUNK = 100352 — reused as fill cursors
    int* bsum   = ibase + 200708;   // 128
    int* boffs  = ibase + 200836;   // 128
    int* csr    = ibase + 200964;   // E

    size_t needed = (size_t)(2L * NN * FD + 512) * 4 + (size_t)(200964 + E) * 4;

    const int n4 = NN * FD / 4;

    if (ws_size >= needed) {
        // ---- CSR path ----
        k_zero2<<<(NCH * CHUNK + 255) / 256, 256, 0, stream>>>(cnt, NCH * CHUNK, S, 192);
        // build CSR by dst
        k_hist<<<2048, 256, 0, stream>>>(ei, cnt, E);
        k_scanA<<<NCH, 256, 0, stream>>>((const int4*)cnt, rowptr, bsum);
        k_scanB<<<1, 128, 0, stream>>>(bsum, boffs);
        k_scanC<<<NCH, 256, 0, stream>>>(rowptr, boffs, cnt);
        k_fill<<<2048, 256, 0, stream>>>(ei, cnt, csr, E);

        // conv1: agg = x + gather(x)
        k_gather<<<25000, 256, 0, stream>>>(x, rowptr, csr, nullptr, nullptr, agg, E);
        // conv1 MLP -> h1 (+ BN1 stats)
        k_mlp64<<<(NN + 255) / 256, 256, 0, stream>>>(agg, W1a, b1a, W1b, b1b, h1, gsum1, gsq1);
        k_bnfin<<<1, 64, 0, stream>>>(gsum1, gsq1, g1, be1, scale1, shift1, 64, 1.f / NN);
        // conv5: agg = bn(h1) + gather(bn(h1))  [affine folded]
        k_gather<<<25000, 256, 0, stream>>>(h1, rowptr, csr, scale1, shift1, agg, E);
        // conv5 MLP -> out (+ BN2 stats)
        k_mlp_out<<<(NN + 255) / 256, 256, 0, stream>>>(agg, W5a, b5a, W5b, b5b, out, gsum2, gsq2);
        k_bnfin<<<1, 64, 0, stream>>>(gsum2, gsq2, g5, be5, scale2, shift2, OUTF, 1.f / NN);
        k_bn_apply2<<<(NN * OUTF + 255) / 256, 256, 0, stream>>>(out, scale2, shift2, NN * OUTF);
    } else {
        // ---- fallback: round-1 atomic path ----
        k_zero<<<1, 256, 0, stream>>>(S, 192);
        k_copy4<<<4096, 256, 0, stream>>>((const float4*)x, (float4*)agg, n4);
        k_scatter<<<4096, 256, 0, stream>>>(x, ei, agg, E);
        k_mlp64<<<(NN + 255) / 256, 256, 0, stream>>>(agg, W1a, b1a, W1b, b1b, h1, gsum1, gsq1);
        k_bnfin<<<1, 64, 0, stream>>>(gsum1, gsq1, g1, be1, scale1, shift1, 64, 1.f / NN);
        k_bn_copy<<<4096, 256, 0, stream>>>((const float4*)h1, (const float4*)scale1,
                                            (const float4*)shift1, (float4*)agg, n4);
        k_scatter_bn<<<4096, 256, 0, stream>>>(h1, ei, scale1, shift1, agg, E);
        k_mlp_out<<<(NN + 255) / 256, 256, 0, stream>>>(agg, W5a, b5a, W5b, b5b, out, gsum2, gsq2);
        k_bnfin<<<1, 64, 0, stream>>>(gsum2, gsq2, g5, be5, scale2, shift2, OUTF, 1.f / NN);
        k_bn_apply2<<<(NN * OUTF + 255) / 256, 256, 0, stream>>>(out, scale2, shift2, NN * OUTF);
    }
}

// Round 4
// 438.793 us; speedup vs baseline: 2.0385x; 1.3624x over previous
//
#include <hip/hip_runtime.h>

#define NN 100000
#define FD 64
#define OUTF 2
#define NB 391        // ceil(NN/256) dst buckets, bucket = d >> 8
#define P1CH 4096     // edges per block in partition kernels
#define NP1 391       // ceil(E/P1CH) for E=1.6M (runtime-guarded anyway)

// ---------------- utility kernels ----------------

__global__ void k_zero(float* __restrict__ p, int n) {
    int i = blockIdx.x * blockDim.x + threadIdx.x;
    if (i < n) p[i] = 0.f;
}

__global__ void k_zero2(int* __restrict__ a, int na, float* __restrict__ b, int nb) {
    int i = blockIdx.x * blockDim.x + threadIdx.x;
    if (i < na) a[i] = 0;
    if (i < nb) b[i] = 0.f;
}

__global__ void k_copy4(const float4* __restrict__ s, float4* __restrict__ d, int n4) {
    int i = blockIdx.x * blockDim.x + threadIdx.x;
    int st = gridDim.x * blockDim.x;
    for (; i < n4; i += st) d[i] = s[i];
}

// ---------------- bucket-partitioned CSR build ----------------
// Round-3 k_fill was bound by returning-global-atomic 64B write-through
// (1.6M ops -> 106 MB WRITE_SIZE). This build keeps per-edge returning
// atomics in LDS; global returning atomics only per (block x bucket).

// pass 1a: bucket histogram (LDS-aggregated, non-returning global adds)
__global__ __launch_bounds__(256) void k_p1a(const int* __restrict__ ei,
                                             int* __restrict__ gcnt, int E_) {
    __shared__ int h[NB];
    int tid = threadIdx.x;
    for (int i = tid; i < NB; i += 256) h[i] = 0;
    __syncthreads();
    int c0 = blockIdx.x * P1CH;
    int c1 = min(c0 + P1CH, E_);
    for (int i = c0 + tid; i < c1; i += 256) {
        int d = ei[E_ + i];
        int b = min(max(d >> 8, 0), NB - 1);
        atomicAdd(&h[b], 1);
    }
    __syncthreads();
    for (int i = tid; i < NB; i += 256) {
        int c = h[i];
        if (c) atomicAdd(&gcnt[i], c);
    }
}

// pass 1 scan: bucket sizes -> bases + cursors (single block, 512 threads)
__global__ __launch_bounds__(512) void k_p1scan(const int* __restrict__ gcnt,
                                                int* __restrict__ bbase,
                                                int* __restrict__ bcur) {
    __shared__ int ts[512];
    int tid = threadIdx.x;
    int v = (tid < NB) ? gcnt[tid] : 0;
    ts[tid] = v;
    __syncthreads();
    for (int off = 1; off < 512; off <<= 1) {
        int u = (tid >= off) ? ts[tid - off] : 0;
        __syncthreads();
        ts[tid] += u;
        __syncthreads();
    }
    int excl = ts[tid] - v;
    if (tid < NB) {
        bbase[tid] = excl;
        bcur[tid] = excl;
    }
    if (tid == 511) bbase[NB] = ts[511];  // = E
}

// pass 1b: partition edges into bucket-grouped part[] (packed (d&255)<<20 | s)
__global__ __launch_bounds__(256) void k_p1b(const int* __restrict__ ei,
                                             int* __restrict__ bcur,
                                             int* __restrict__ part, int E_) {
    __shared__ int h[NB];
    __shared__ int base[NB];
    int tid = threadIdx.x;
    for (int i = tid; i < NB; i += 256) h[i] = 0;
    __syncthreads();
    int c0 = blockIdx.x * P1CH;
    int c1 = min(c0 + P1CH, E_);
    for (int i = c0 + tid; i < c1; i += 256) {
        int d = ei[E_ + i];
        int b = min(max(d >> 8, 0), NB - 1);
        atomicAdd(&h[b], 1);
    }
    __syncthreads();
    for (int i = tid; i < NB; i += 256) {
        int c = h[i];
        base[i] = c ? atomicAdd(&bcur[i], c) : 0;  // returning, per block x bucket only
        h[i] = 0;
    }
    __syncthreads();
    for (int i = c0 + tid; i < c1; i += 256) {
        int s = ei[i];
        int d = ei[E_ + i];
        int b = min(max(d >> 8, 0), NB - 1);
        int slot = base[b] + atomicAdd(&h[b], 1);  // LDS returning atomic
        part[slot] = ((d & 255) << 20) | (s & 0xFFFFF);
    }
}

// pass 2: per-bucket (256 nodes) local counting sort -> rowptr + csr
__global__ __launch_bounds__(256) void k_build(const int* __restrict__ part,
                                               const int* __restrict__ bbase,
                                               int* __restrict__ rowptr,
                                               int* __restrict__ csr, int E_) {
    __shared__ int cnt[256];
    __shared__ int ts[256];
    __shared__ int cur[256];
    int b = blockIdx.x;
    int tid = threadIdx.x;
    cnt[tid] = 0;
    __syncthreads();
    int s0 = bbase[b], s1 = bbase[b + 1];
    for (int i = s0 + tid; i < s1; i += 256) {
        int v = part[i];
        atomicAdd(&cnt[(v >> 20) & 255], 1);
    }
    __syncthreads();
    int v = cnt[tid];
    ts[tid] = v;
    __syncthreads();
    for (int off = 1; off < 256; off <<= 1) {
        int u = (tid >= off) ? ts[tid - off] : 0;
        __syncthreads();
        ts[tid] += u;
        __syncthreads();
    }
    int excl = ts[tid] - v;
    int node = b * 256 + tid;
    if (node < NN) rowptr[node] = s0 + excl;
    cur[tid] = s0 + excl;
    if (b == 0 && tid == 0) rowptr[NN] = E_;
    __syncthreads();
    for (int i = s0 + tid; i < s1; i += 256) {
        int v2 = part[i];
        int lj = (v2 >> 20) & 255;
        int pos = atomicAdd(&cur[lj], 1);  // LDS returning atomic
        csr[pos] = v2 & 0xFFFFF;
    }
}

// ---------------- gather aggregation ----------------
// one wave per node, lane = feature; 4 independent accumulator chains for MLP
// out[n] = X[n] + sum_{s in N(n)} X[s]; optional affine epilogue.
__global__ __launch_bounds__(256) void k_gather(const float* __restrict__ X,
                                                const int* __restrict__ rowptr,
                                                const int* __restrict__ csr,
                                                const float* __restrict__ sc,
                                                const float* __restrict__ sh,
                                                float* __restrict__ out, int E_) {
    int lane = threadIdx.x & 63;
    int n = (blockIdx.x * blockDim.x + threadIdx.x) >> 6;
    if (n >= NN) return;
    int start = rowptr[n], end = rowptr[n + 1];
    start = min(max(start, 0), E_);
    end = min(max(end, start), E_);
    float acc0 = X[(long)n * FD + lane];
    float acc1 = 0.f, acc2 = 0.f, acc3 = 0.f;
    int i = start;
    for (; i + 64 <= end; i += 64) {
        int id = min(max(csr[i + lane], 0), NN - 1);
#pragma unroll
        for (int j = 0; j < 64; j += 4) {
            int t0 = __shfl(id, j + 0);
            int t1 = __shfl(id, j + 1);
            int t2 = __shfl(id, j + 2);
            int t3 = __shfl(id, j + 3);
            acc0 += X[(long)t0 * FD + lane];
            acc1 += X[(long)t1 * FD + lane];
            acc2 += X[(long)t2 * FD + lane];
            acc3 += X[(long)t3 * FD + lane];
        }
    }
    int rem = end - i;
    if (rem > 0) {
        int id = 0;
        if (lane < rem) id = min(max(csr[i + lane], 0), NN - 1);
        int j = 0;
        for (; j + 4 <= rem; j += 4) {
            int t0 = __shfl(id, j + 0);
            int t1 = __shfl(id, j + 1);
            int t2 = __shfl(id, j + 2);
            int t3 = __shfl(id, j + 3);
            acc0 += X[(long)t0 * FD + lane];
            acc1 += X[(long)t1 * FD + lane];
            acc2 += X[(long)t2 * FD + lane];
            acc3 += X[(long)t3 * FD + lane];
        }
        for (; j < rem; j++) {
            int t0 = __shfl(id, j);
            acc0 += X[(long)t0 * FD + lane];
        }
    }
    float acc = (acc0 + acc1) + (acc2 + acc3);
    if (sc) {
        int deg = end - start;
        acc = fmaf(acc, sc[lane], (float)(deg + 1) * sh[lane]);
    }
    out[(long)n * FD + lane] = acc;
}

// ---------------- MLP kernels (BN stats fused into epilogue) ----------------

__global__ __launch_bounds__(256) void k_mlp64(
        const float* __restrict__ X,
        const float* __restrict__ Wa, const float* __restrict__ ba,
        const float* __restrict__ Wb, const float* __restrict__ bb,
        float* __restrict__ H, float* __restrict__ gsum, float* __restrict__ gsq) {
    __shared__ float row[256 * 65];
    int tid = threadIdx.x;
    long node = (long)blockIdx.x * 256 + tid;
    bool valid = node < NN;
    if (valid) {
        const float4* rp = (const float4*)(X + node * FD);
#pragma unroll
        for (int q = 0; q < 16; q++) {
            float4 v = rp[q];
            row[tid * 65 + 4 * q + 0] = v.x;
            row[tid * 65 + 4 * q + 1] = v.y;
            row[tid * 65 + 4 * q + 2] = v.z;
            row[tid * 65 + 4 * q + 3] = v.w;
        }
    }
    float acc[64];
#pragma unroll
    for (int j = 0; j < 64; j++) acc[j] = ba[j];
    if (valid) {
        for (int k = 0; k < 64; k++) {
            float xv = row[tid * 65 + k];
            const float* wr = Wa + k * 64;
#pragma unroll
            for (int j = 0; j < 64; j++) acc[j] = fmaf(xv, wr[j], acc[j]);
        }
    }
#pragma unroll
    for (int j = 0; j < 64; j++) row[tid * 65 + j] = fmaxf(acc[j], 0.f);
#pragma unroll
    for (int j = 0; j < 64; j++) acc[j] = bb[j];
    if (valid) {
        for (int k = 0; k < 64; k++) {
            float xv = row[tid * 65 + k];
            const float* wr = Wb + k * 64;
#pragma unroll
            for (int j = 0; j < 64; j++) acc[j] = fmaf(xv, wr[j], acc[j]);
        }
    }
#pragma unroll
    for (int j = 0; j < 64; j++) {
        float v = valid ? fmaxf(acc[j], 0.f) : 0.f;
        row[tid * 65 + j] = v;
    }
    if (valid) {
        float4* op = (float4*)(H + node * FD);
#pragma unroll
        for (int q = 0; q < 16; q++) {
            float4 v;
            v.x = row[tid * 65 + 4 * q + 0];
            v.y = row[tid * 65 + 4 * q + 1];
            v.z = row[tid * 65 + 4 * q + 2];
            v.w = row[tid * 65 + 4 * q + 3];
            op[q] = v;
        }
    }
    __syncthreads();
    if (tid < 64) {
        float s = 0.f, q = 0.f;
        for (int r = 0; r < 256; r++) {
            float v = row[r * 65 + tid];
            s += v;
            q += v * v;
        }
        atomicAdd(&gsum[tid], s);
        atomicAdd(&gsq[tid], q);
    }
}

__global__ __launch_bounds__(256) void k_mlp_out(
        const float* __restrict__ X,
        const float* __restrict__ Wa, const float* __restrict__ ba,
        const float* __restrict__ Wb, const float* __restrict__ bb,
        float* __restrict__ O, float* __restrict__ gsum, float* __restrict__ gsq) {
    __shared__ float row[256 * 65];
    __shared__ float red[256][4];
    int tid = threadIdx.x;
    long node = (long)blockIdx.x * 256 + tid;
    bool valid = node < NN;
    if (valid) {
        const float4* rp = (const float4*)(X + node * FD);
#pragma unroll
        for (int q = 0; q < 16; q++) {
            float4 v = rp[q];
            row[tid * 65 + 4 * q + 0] = v.x;
            row[tid * 65 + 4 * q + 1] = v.y;
            row[tid * 65 + 4 * q + 2] = v.z;
            row[tid * 65 + 4 * q + 3] = v.w;
        }
    }
    float acc[64];
#pragma unroll
    for (int j = 0; j < 64; j++) acc[j] = ba[j];
    if (valid) {
        for (int k = 0; k < 64; k++) {
            float xv = row[tid * 65 + k];
            const float* wr = Wa + k * 64;
#pragma unroll
            for (int j = 0; j < 64; j++) acc[j] = fmaf(xv, wr[j], acc[j]);
        }
    }
#pragma unroll
    for (int j = 0; j < 64; j++) row[tid * 65 + j] = fmaxf(acc[j], 0.f);
    float a0 = bb[0];
    float a1 = bb[1];
    if (valid) {
        for (int k = 0; k < 64; k++) {
            float xv = row[tid * 65 + k];
            a0 = fmaf(xv, Wb[k * 2 + 0], a0);
            a1 = fmaf(xv, Wb[k * 2 + 1], a1);
        }
    }
    float v0 = valid ? fmaxf(a0, 0.f) : 0.f;
    float v1 = valid ? fmaxf(a1, 0.f) : 0.f;
    if (valid) {
        float2 v;
        v.x = v0;
        v.y = v1;
        ((float2*)O)[node] = v;
    }
    red[tid][0] = v0;
    red[tid][1] = v0 * v0;
    red[tid][2] = v1;
    red[tid][3] = v1 * v1;
    __syncthreads();
    for (int off = 128; off > 0; off >>= 1) {
        if (tid < off) {
#pragma unroll
            for (int c = 0; c < 4; c++) red[tid][c] += red[tid + off][c];
        }
        __syncthreads();
    }
    if (tid == 0) {
        atomicAdd(&gsum[0], red[0][0]);
        atomicAdd(&gsq[0], red[0][1]);
        atomicAdd(&gsum[1], red[0][2]);
        atomicAdd(&gsq[1], red[0][3]);
    }
}

// ---------------- batchnorm finalize / apply ----------------

__global__ void k_bnfin(const float* __restrict__ gsum, const float* __restrict__ gsq,
                        const float* __restrict__ g, const float* __restrict__ be,
                        float* __restrict__ sc, float* __restrict__ sh, int C, float invN) {
    int c = threadIdx.x;
    if (c < C) {
        float mu = gsum[c] * invN;
        float var = gsq[c] * invN - mu * mu;
        float s = g[c] * rsqrtf(var + 1e-5f);
        sc[c] = s;
        sh[c] = fmaf(-mu, s, be[c]);
    }
}

__global__ void k_bn_apply2(float* __restrict__ o, const float* __restrict__ sc,
                            const float* __restrict__ sh, int n) {
    int i = blockIdx.x * blockDim.x + threadIdx.x;
    if (i < n) {
        int c = i & 1;
        o[i] = fmaf(o[i], sc[c], sh[c]);
    }
}

// ---------------- fallback (round-1) atomic scatter kernels ----------------

__global__ void k_scatter(const float* __restrict__ x, const int* __restrict__ ei,
                          float* __restrict__ agg, int E_) {
    int lane = threadIdx.x & 63;
    int wid = (blockIdx.x * blockDim.x + threadIdx.x) >> 6;
    int nw = (gridDim.x * blockDim.x) >> 6;
    for (long e = wid; e < E_; e += nw) {
        int s = ei[e];
        int d = ei[E_ + e];
        float v = x[(long)s * FD + lane];
        atomicAdd(&agg[(long)d * FD + lane], v);
    }
}

__global__ void k_scatter_bn(const float* __restrict__ h, const int* __restrict__ ei,
                             const float* __restrict__ sc, const float* __restrict__ sh,
                             float* __restrict__ agg, int E_) {
    int lane = threadIdx.x & 63;
    float scl = sc[lane];
    float shf = sh[lane];
    int wid = (blockIdx.x * blockDim.x + threadIdx.x) >> 6;
    int nw = (gridDim.x * blockDim.x) >> 6;
    for (long e = wid; e < E_; e += nw) {
        int s = ei[e];
        int d = ei[E_ + e];
        float v = fmaf(h[(long)s * FD + lane], scl, shf);
        atomicAdd(&agg[(long)d * FD + lane], v);
    }
}

__global__ void k_bn_copy(const float4* __restrict__ h, const float4* __restrict__ sc4,
                          const float4* __restrict__ sh4, float4* __restrict__ o, int n4) {
    int i = blockIdx.x * blockDim.x + threadIdx.x;
    int st = gridDim.x * blockDim.x;
    for (; i < n4; i += st) {
        float4 v = h[i];
        int c = i & 15;
        float4 s = sc4[c];
        float4 b = sh4[c];
        v.x = fmaf(v.x, s.x, b.x);
        v.y = fmaf(v.y, s.y, b.y);
        v.z = fmaf(v.z, s.z, b.z);
        v.w = fmaf(v.w, s.w, b.w);
        o[i] = v;
    }
}

// ---------------- launch ----------------

extern "C" void kernel_launch(void* const* d_in, const int* in_sizes, int n_in,
                              void* d_out, int out_size, void* d_ws, size_t ws_size,
                              hipStream_t stream) {
    const float* x   = (const float*)d_in[0];
    const int*   ei  = (const int*)d_in[1];
    const float* W1a = (const float*)d_in[2];
    const float* b1a = (const float*)d_in[3];
    const float* W1b = (const float*)d_in[4];
    const float* b1b = (const float*)d_in[5];
    const float* g1  = (const float*)d_in[6];
    const float* be1 = (const float*)d_in[7];
    const float* W5a = (const float*)d_in[8];
    const float* b5a = (const float*)d_in[9];
    const float* W5b = (const float*)d_in[10];
    const float* b5b = (const float*)d_in[11];
    const float* g5  = (const float*)d_in[12];
    const float* be5 = (const float*)d_in[13];
    float* out = (float*)d_out;

    const int E = in_sizes[1] / 2;

    float* ws = (float*)d_ws;
    float* agg = ws;                   // [N*64]; first E ints aliased as part[]
    float* h1  = ws + (long)NN * FD;   // [N*64]
    float* S   = ws + 2L * NN * FD;    // 512 floats: stats & bn params
    float* gsum1  = S;        // 64
    float* gsq1   = S + 64;   // 64
    float* gsum2  = S + 128;  // 2
    float* gsq2   = S + 160;  // 2
    float* scale1 = S + 192;  // 64
    float* shift1 = S + 256;  // 64
    float* scale2 = S + 320;  // 2
    float* shift2 = S + 328;  // 2

    int* ibase  = (int*)(S + 512);
    int* rowptr = ibase;                  // NN+1 (padded to 100004)
    int* csr    = ibase + 100004;         // E
    int* gcnt   = ibase + 100004 + E;     // NB
    int* bbase  = gcnt + 392;             // NB+1
    int* bcur   = bbase + 396;            // NB
    int* part   = (int*)agg;              // E ints, aliased with agg (used before agg)

    size_t needed = (size_t)(2L * NN * FD + 512) * 4 + (size_t)(100004 + E + 392 + 396 + 396) * 4;

    const int n4 = NN * FD / 4;
    const int np1 = (E + P1CH - 1) / P1CH;

    if (ws_size >= needed) {
        // ---- bucket-partitioned CSR path ----
        k_zero2<<<2, 256, 0, stream>>>(gcnt, NB, S, 192);
        k_p1a<<<np1, 256, 0, stream>>>(ei, gcnt, E);
        k_p1scan<<<1, 512, 0, stream>>>(gcnt, bbase, bcur);
        k_p1b<<<np1, 256, 0, stream>>>(ei, bcur, part, E);
        k_build<<<NB, 256, 0, stream>>>(part, bbase, rowptr, csr, E);

        // conv1: agg = x + gather(x)   (agg overwrites part — part no longer needed)
        k_gather<<<25000, 256, 0, stream>>>(x, rowptr, csr, nullptr, nullptr, agg, E);
        // conv1 MLP -> h1 (+ BN1 stats)
        k_mlp64<<<(NN + 255) / 256, 256, 0, stream>>>(agg, W1a, b1a, W1b, b1b, h1, gsum1, gsq1);
        k_bnfin<<<1, 64, 0, stream>>>(gsum1, gsq1, g1, be1, scale1, shift1, 64, 1.f / NN);
        // conv5: agg = bn(h1) + gather(bn(h1))  [affine folded]
        k_gather<<<25000, 256, 0, stream>>>(h1, rowptr, csr, scale1, shift1, agg, E);
        // conv5 MLP -> out (+ BN2 stats)
        k_mlp_out<<<(NN + 255) / 256, 256, 0, stream>>>(agg, W5a, b5a, W5b, b5b, out, gsum2, gsq2);
        k_bnfin<<<1, 64, 0, stream>>>(gsum2, gsq2, g5, be5, scale2, shift2, OUTF, 1.f / NN);
        k_bn_apply2<<<(NN * OUTF + 255) / 256, 256, 0, stream>>>(out, scale2, shift2, NN * OUTF);
    } else {
        // ---- fallback: round-1 atomic path ----
        k_zero<<<1, 256, 0, stream>>>(S, 192);
        k_copy4<<<4096, 256, 0, stream>>>((const float4*)x, (float4*)agg, n4);
        k_scatter<<<4096, 256, 0, stream>>>(x, ei, agg, E);
        k_mlp64<<<(NN + 255) / 256, 256, 0, stream>>>(agg, W1a, b1a, W1b, b1b, h1, gsum1, gsq1);
        k_bnfin<<<1, 64, 0, stream>>>(gsum1, gsq1, g1, be1, scale1, shift1, 64, 1.f / NN);
        k_bn_copy<<<4096, 256, 0, stream>>>((const float4*)h1, (const float4*)scale1,
                                            (const float4*)shift1, (float4*)agg, n4);
        k_scatter_bn<<<4096, 256, 0, stream>>>(h1, ei, scale1, shift1, agg, E);
        k_mlp_out<<<(NN + 255) / 256, 256, 0, stream>>>(agg, W5a, b5a, W5b, b5b, out, gsum2, gsq2);
        k_bnfin<<<1, 64, 0, stream>>>(gsum2, gsq2, g5, be5, scale2, shift2, OUTF, 1.f / NN);
        k_bn_apply2<<<(NN * OUTF + 255) / 256, 256, 0, stream>>>(out, scale2, shift2, NN * OUTF);
    }
}

// Round 5
// 381.275 us; speedup vs baseline: 2.3461x; 1.1509x over previous
//
#include <hip/hip_runtime.h>

#define NN 100000
#define FD 64
#define OUTF 2
#define NB 391        // ceil(NN/256) dst buckets, bucket = d >> 8
#define P1CH 4096     // edges per block in partition kernels

// bf16 helpers (round-to-nearest-even)
__device__ inline ushort f2bf(float f) {
    uint u = __float_as_uint(f);
    uint r = (u + 0x7FFFu + ((u >> 16) & 1u)) >> 16;
    return (ushort)r;
}
__device__ inline float bf2f(ushort v) {
    return __uint_as_float(((uint)v) << 16);
}

// ---------------- utility kernels ----------------

__global__ void k_zero(float* __restrict__ p, int n) {
    int i = blockIdx.x * blockDim.x + threadIdx.x;
    if (i < n) p[i] = 0.f;
}

__global__ void k_zero2(int* __restrict__ a, int na, float* __restrict__ b, int nb) {
    int i = blockIdx.x * blockDim.x + threadIdx.x;
    if (i < na) a[i] = 0;
    if (i < nb) b[i] = 0.f;
}

__global__ void k_copy4(const float4* __restrict__ s, float4* __restrict__ d, int n4) {
    int i = blockIdx.x * blockDim.x + threadIdx.x;
    int st = gridDim.x * blockDim.x;
    for (; i < n4; i += st) d[i] = s[i];
}

// f32 -> bf16 conversion copy
__global__ void k_cvt(const float4* __restrict__ x4, ushort4* __restrict__ xb4, int n4) {
    int i = blockIdx.x * blockDim.x + threadIdx.x;
    int st = gridDim.x * blockDim.x;
    for (; i < n4; i += st) {
        float4 v = x4[i];
        ushort4 w;
        w.x = f2bf(v.x);
        w.y = f2bf(v.y);
        w.z = f2bf(v.z);
        w.w = f2bf(v.w);
        xb4[i] = w;
    }
}

// ---------------- bucket-partitioned CSR build ----------------

__global__ __launch_bounds__(256) void k_p1a(const int* __restrict__ ei,
                                             int* __restrict__ gcnt, int E_) {
    __shared__ int h[NB];
    int tid = threadIdx.x;
    for (int i = tid; i < NB; i += 256) h[i] = 0;
    __syncthreads();
    int c0 = blockIdx.x * P1CH;
    int c1 = min(c0 + P1CH, E_);
    for (int i = c0 + tid; i < c1; i += 256) {
        int d = ei[E_ + i];
        int b = min(max(d >> 8, 0), NB - 1);
        atomicAdd(&h[b], 1);
    }
    __syncthreads();
    for (int i = tid; i < NB; i += 256) {
        int c = h[i];
        if (c) atomicAdd(&gcnt[i], c);
    }
}

__global__ __launch_bounds__(512) void k_p1scan(const int* __restrict__ gcnt,
                                                int* __restrict__ bbase,
                                                int* __restrict__ bcur) {
    __shared__ int ts[512];
    int tid = threadIdx.x;
    int v = (tid < NB) ? gcnt[tid] : 0;
    ts[tid] = v;
    __syncthreads();
    for (int off = 1; off < 512; off <<= 1) {
        int u = (tid >= off) ? ts[tid - off] : 0;
        __syncthreads();
        ts[tid] += u;
        __syncthreads();
    }
    int excl = ts[tid] - v;
    if (tid < NB) {
        bbase[tid] = excl;
        bcur[tid] = excl;
    }
    if (tid == 511) bbase[NB] = ts[511];  // = E
}

__global__ __launch_bounds__(256) void k_p1b(const int* __restrict__ ei,
                                             int* __restrict__ bcur,
                                             int* __restrict__ part, int E_) {
    __shared__ int h[NB];
    __shared__ int base[NB];
    int tid = threadIdx.x;
    for (int i = tid; i < NB; i += 256) h[i] = 0;
    __syncthreads();
    int c0 = blockIdx.x * P1CH;
    int c1 = min(c0 + P1CH, E_);
    for (int i = c0 + tid; i < c1; i += 256) {
        int d = ei[E_ + i];
        int b = min(max(d >> 8, 0), NB - 1);
        atomicAdd(&h[b], 1);
    }
    __syncthreads();
    for (int i = tid; i < NB; i += 256) {
        int c = h[i];
        base[i] = c ? atomicAdd(&bcur[i], c) : 0;  // returning, per block x bucket
        h[i] = 0;
    }
    __syncthreads();
    for (int i = c0 + tid; i < c1; i += 256) {
        int s = ei[i];
        int d = ei[E_ + i];
        int b = min(max(d >> 8, 0), NB - 1);
        int slot = base[b] + atomicAdd(&h[b], 1);  // LDS returning atomic
        part[slot] = ((d & 255) << 20) | (s & 0xFFFFF);
    }
}

__global__ __launch_bounds__(256) void k_build(const int* __restrict__ part,
                                               const int* __restrict__ bbase,
                                               int* __restrict__ rowptr,
                                               int* __restrict__ csr, int E_) {
    __shared__ int cnt[256];
    __shared__ int ts[256];
    __shared__ int cur[256];
    int b = blockIdx.x;
    int tid = threadIdx.x;
    cnt[tid] = 0;
    __syncthreads();
    int s0 = bbase[b], s1 = bbase[b + 1];
    for (int i = s0 + tid; i < s1; i += 256) {
        int v = part[i];
        atomicAdd(&cnt[(v >> 20) & 255], 1);
    }
    __syncthreads();
    int v = cnt[tid];
    ts[tid] = v;
    __syncthreads();
    for (int off = 1; off < 256; off <<= 1) {
        int u = (tid >= off) ? ts[tid - off] : 0;
        __syncthreads();
        ts[tid] += u;
        __syncthreads();
    }
    int excl = ts[tid] - v;
    int node = b * 256 + tid;
    if (node < NN) rowptr[node] = s0 + excl;
    cur[tid] = s0 + excl;
    if (b == 0 && tid == 0) rowptr[NN] = E_;
    __syncthreads();
    for (int i = s0 + tid; i < s1; i += 256) {
        int v2 = part[i];
        int lj = (v2 >> 20) & 255;
        int pos = atomicAdd(&cur[lj], 1);  // LDS returning atomic
        csr[pos] = v2 & 0xFFFFF;
    }
}

// ---------------- gather aggregation (bf16 source, f32 accumulate) ----------------
// one wave per node, lane = feature; 4 independent accumulator chains.
// out[n] = X[n] + sum_{s in N(n)} X[s]; optional affine epilogue (BN fold).
__global__ __launch_bounds__(256) void k_gather_bf(const ushort* __restrict__ Xb,
                                                   const int* __restrict__ rowptr,
                                                   const int* __restrict__ csr,
                                                   const float* __restrict__ sc,
                                                   const float* __restrict__ sh,
                                                   float* __restrict__ out, int E_) {
    int lane = threadIdx.x & 63;
    int n = (blockIdx.x * blockDim.x + threadIdx.x) >> 6;
    if (n >= NN) return;
    int start = rowptr[n], end = rowptr[n + 1];
    start = min(max(start, 0), E_);
    end = min(max(end, start), E_);
    float acc0 = bf2f(Xb[(long)n * FD + lane]);
    float acc1 = 0.f, acc2 = 0.f, acc3 = 0.f;
    int i = start;
    for (; i + 64 <= end; i += 64) {
        int id = min(max(csr[i + lane], 0), NN - 1);
#pragma unroll
        for (int j = 0; j < 64; j += 4) {
            int t0 = __shfl(id, j + 0);
            int t1 = __shfl(id, j + 1);
            int t2 = __shfl(id, j + 2);
            int t3 = __shfl(id, j + 3);
            acc0 += bf2f(Xb[(long)t0 * FD + lane]);
            acc1 += bf2f(Xb[(long)t1 * FD + lane]);
            acc2 += bf2f(Xb[(long)t2 * FD + lane]);
            acc3 += bf2f(Xb[(long)t3 * FD + lane]);
        }
    }
    int rem = end - i;
    if (rem > 0) {
        int id = 0;
        if (lane < rem) id = min(max(csr[i + lane], 0), NN - 1);
        int j = 0;
        for (; j + 4 <= rem; j += 4) {
            int t0 = __shfl(id, j + 0);
            int t1 = __shfl(id, j + 1);
            int t2 = __shfl(id, j + 2);
            int t3 = __shfl(id, j + 3);
            acc0 += bf2f(Xb[(long)t0 * FD + lane]);
            acc1 += bf2f(Xb[(long)t1 * FD + lane]);
            acc2 += bf2f(Xb[(long)t2 * FD + lane]);
            acc3 += bf2f(Xb[(long)t3 * FD + lane]);
        }
        for (; j < rem; j++) {
            int t0 = __shfl(id, j);
            acc0 += bf2f(Xb[(long)t0 * FD + lane]);
        }
    }
    float acc = (acc0 + acc1) + (acc2 + acc3);
    if (sc) {
        int deg = end - start;
        acc = fmaf(acc, sc[lane], (float)(deg + 1) * sh[lane]);
    }
    out[(long)n * FD + lane] = acc;
}

// ---------------- MLP kernels (BN stats fused into epilogue) ----------------
// BF16OUT: H is bf16 (ushort*); else f32 (float*). Stats always from exact f32.
template <bool BF16OUT>
__global__ __launch_bounds__(256) void k_mlp64(
        const float* __restrict__ X,
        const float* __restrict__ Wa, const float* __restrict__ ba,
        const float* __restrict__ Wb, const float* __restrict__ bb,
        void* __restrict__ Hv, float* __restrict__ gsum, float* __restrict__ gsq) {
    __shared__ float row[256 * 65];
    int tid = threadIdx.x;
    long node = (long)blockIdx.x * 256 + tid;
    bool valid = node < NN;
    if (valid) {
        const float4* rp = (const float4*)(X + node * FD);
#pragma unroll
        for (int q = 0; q < 16; q++) {
            float4 v = rp[q];
            row[tid * 65 + 4 * q + 0] = v.x;
            row[tid * 65 + 4 * q + 1] = v.y;
            row[tid * 65 + 4 * q + 2] = v.z;
            row[tid * 65 + 4 * q + 3] = v.w;
        }
    }
    float acc[64];
#pragma unroll
    for (int j = 0; j < 64; j++) acc[j] = ba[j];
    if (valid) {
        for (int k = 0; k < 64; k++) {
            float xv = row[tid * 65 + k];
            const float* wr = Wa + k * 64;
#pragma unroll
            for (int j = 0; j < 64; j++) acc[j] = fmaf(xv, wr[j], acc[j]);
        }
    }
#pragma unroll
    for (int j = 0; j < 64; j++) row[tid * 65 + j] = fmaxf(acc[j], 0.f);
#pragma unroll
    for (int j = 0; j < 64; j++) acc[j] = bb[j];
    if (valid) {
        for (int k = 0; k < 64; k++) {
            float xv = row[tid * 65 + k];
            const float* wr = Wb + k * 64;
#pragma unroll
            for (int j = 0; j < 64; j++) acc[j] = fmaf(xv, wr[j], acc[j]);
        }
    }
#pragma unroll
    for (int j = 0; j < 64; j++) {
        float v = valid ? fmaxf(acc[j], 0.f) : 0.f;
        row[tid * 65 + j] = v;
    }
    if (valid) {
        if (BF16OUT) {
            ushort4* op = (ushort4*)((ushort*)Hv + node * FD);
#pragma unroll
            for (int q = 0; q < 16; q++) {
                ushort4 w;
                w.x = f2bf(row[tid * 65 + 4 * q + 0]);
                w.y = f2bf(row[tid * 65 + 4 * q + 1]);
                w.z = f2bf(row[tid * 65 + 4 * q + 2]);
                w.w = f2bf(row[tid * 65 + 4 * q + 3]);
                op[q] = w;
            }
        } else {
            float4* op = (float4*)((float*)Hv + node * FD);
#pragma unroll
            for (int q = 0; q < 16; q++) {
                float4 v;
                v.x = row[tid * 65 + 4 * q + 0];
                v.y = row[tid * 65 + 4 * q + 1];
                v.z = row[tid * 65 + 4 * q + 2];
                v.w = row[tid * 65 + 4 * q + 3];
                op[q] = v;
            }
        }
    }
    __syncthreads();
    if (tid < 64) {
        float s = 0.f, q = 0.f;
        for (int r = 0; r < 256; r++) {
            float v = row[r * 65 + tid];
            s += v;
            q += v * v;
        }
        atomicAdd(&gsum[tid], s);
        atomicAdd(&gsq[tid], q);
    }
}

__global__ __launch_bounds__(256) void k_mlp_out(
        const float* __restrict__ X,
        const float* __restrict__ Wa, const float* __restrict__ ba,
        const float* __restrict__ Wb, const float* __restrict__ bb,
        float* __restrict__ O, float* __restrict__ gsum, float* __restrict__ gsq) {
    __shared__ float row[256 * 65];
    __shared__ float red[256][4];
    int tid = threadIdx.x;
    long node = (long)blockIdx.x * 256 + tid;
    bool valid = node < NN;
    if (valid) {
        const float4* rp = (const float4*)(X + node * FD);
#pragma unroll
        for (int q = 0; q < 16; q++) {
            float4 v = rp[q];
            row[tid * 65 + 4 * q + 0] = v.x;
            row[tid * 65 + 4 * q + 1] = v.y;
            row[tid * 65 + 4 * q + 2] = v.z;
            row[tid * 65 + 4 * q + 3] = v.w;
        }
    }
    float acc[64];
#pragma unroll
    for (int j = 0; j < 64; j++) acc[j] = ba[j];
    if (valid) {
        for (int k = 0; k < 64; k++) {
            float xv = row[tid * 65 + k];
            const float* wr = Wa + k * 64;
#pragma unroll
            for (int j = 0; j < 64; j++) acc[j] = fmaf(xv, wr[j], acc[j]);
        }
    }
#pragma unroll
    for (int j = 0; j < 64; j++) row[tid * 65 + j] = fmaxf(acc[j], 0.f);
    float a0 = bb[0];
    float a1 = bb[1];
    if (valid) {
        for (int k = 0; k < 64; k++) {
            float xv = row[tid * 65 + k];
            a0 = fmaf(xv, Wb[k * 2 + 0], a0);
            a1 = fmaf(xv, Wb[k * 2 + 1], a1);
        }
    }
    float v0 = valid ? fmaxf(a0, 0.f) : 0.f;
    float v1 = valid ? fmaxf(a1, 0.f) : 0.f;
    if (valid) {
        float2 v;
        v.x = v0;
        v.y = v1;
        ((float2*)O)[node] = v;
    }
    red[tid][0] = v0;
    red[tid][1] = v0 * v0;
    red[tid][2] = v1;
    red[tid][3] = v1 * v1;
    __syncthreads();
    for (int off = 128; off > 0; off >>= 1) {
        if (tid < off) {
#pragma unroll
            for (int c = 0; c < 4; c++) red[tid][c] += red[tid + off][c];
        }
        __syncthreads();
    }
    if (tid == 0) {
        atomicAdd(&gsum[0], red[0][0]);
        atomicAdd(&gsq[0], red[0][1]);
        atomicAdd(&gsum[1], red[0][2]);
        atomicAdd(&gsq[1], red[0][3]);
    }
}

// ---------------- batchnorm finalize / apply ----------------

__global__ void k_bnfin(const float* __restrict__ gsum, const float* __restrict__ gsq,
                        const float* __restrict__ g, const float* __restrict__ be,
                        float* __restrict__ sc, float* __restrict__ sh, int C, float invN) {
    int c = threadIdx.x;
    if (c < C) {
        float mu = gsum[c] * invN;
        float var = gsq[c] * invN - mu * mu;
        float s = g[c] * rsqrtf(var + 1e-5f);
        sc[c] = s;
        sh[c] = fmaf(-mu, s, be[c]);
    }
}

__global__ void k_bn_apply2(float* __restrict__ o, const float* __restrict__ sc,
                            const float* __restrict__ sh, int n) {
    int i = blockIdx.x * blockDim.x + threadIdx.x;
    if (i < n) {
        int c = i & 1;
        o[i] = fmaf(o[i], sc[c], sh[c]);
    }
}

// ---------------- fallback (round-1) atomic scatter kernels ----------------

__global__ void k_scatter(const float* __restrict__ x, const int* __restrict__ ei,
                          float* __restrict__ agg, int E_) {
    int lane = threadIdx.x & 63;
    int wid = (blockIdx.x * blockDim.x + threadIdx.x) >> 6;
    int nw = (gridDim.x * blockDim.x) >> 6;
    for (long e = wid; e < E_; e += nw) {
        int s = ei[e];
        int d = ei[E_ + e];
        float v = x[(long)s * FD + lane];
        atomicAdd(&agg[(long)d * FD + lane], v);
    }
}

__global__ void k_scatter_bn(const float* __restrict__ h, const int* __restrict__ ei,
                             const float* __restrict__ sc, const float* __restrict__ sh,
                             float* __restrict__ agg, int E_) {
    int lane = threadIdx.x & 63;
    float scl = sc[lane];
    float shf = sh[lane];
    int wid = (blockIdx.x * blockDim.x + threadIdx.x) >> 6;
    int nw = (gridDim.x * blockDim.x) >> 6;
    for (long e = wid; e < E_; e += nw) {
        int s = ei[e];
        int d = ei[E_ + e];
        float v = fmaf(h[(long)s * FD + lane], scl, shf);
        atomicAdd(&agg[(long)d * FD + lane], v);
    }
}

__global__ void k_bn_copy(const float4* __restrict__ h, const float4* __restrict__ sc4,
                          const float4* __restrict__ sh4, float4* __restrict__ o, int n4) {
    int i = blockIdx.x * blockDim.x + threadIdx.x;
    int st = gridDim.x * blockDim.x;
    for (; i < n4; i += st) {
        float4 v = h[i];
        int c = i & 15;
        float4 s = sc4[c];
        float4 b = sh4[c];
        v.x = fmaf(v.x, s.x, b.x);
        v.y = fmaf(v.y, s.y, b.y);
        v.z = fmaf(v.z, s.z, b.z);
        v.w = fmaf(v.w, s.w, b.w);
        o[i] = v;
    }
}

// ---------------- launch ----------------

extern "C" void kernel_launch(void* const* d_in, const int* in_sizes, int n_in,
                              void* d_out, int out_size, void* d_ws, size_t ws_size,
                              hipStream_t stream) {
    const float* x   = (const float*)d_in[0];
    const int*   ei  = (const int*)d_in[1];
    const float* W1a = (const float*)d_in[2];
    const float* b1a = (const float*)d_in[3];
    const float* W1b = (const float*)d_in[4];
    const float* b1b = (const float*)d_in[5];
    const float* g1  = (const float*)d_in[6];
    const float* be1 = (const float*)d_in[7];
    const float* W5a = (const float*)d_in[8];
    const float* b5a = (const float*)d_in[9];
    const float* W5b = (const float*)d_in[10];
    const float* b5b = (const float*)d_in[11];
    const float* g5  = (const float*)d_in[12];
    const float* be5 = (const float*)d_in[13];
    float* out = (float*)d_out;

    const int E = in_sizes[1] / 2;

    float* ws = (float*)d_ws;
    float* agg = ws;                         // [N*64] f32; first E ints aliased as part[]
    ushort* xb  = (ushort*)(ws + 6400000);   // [N*64] bf16  (3.2M float-slots)
    ushort* h1b = (ushort*)(ws + 9600000);   // [N*64] bf16  (3.2M float-slots)
    float* h1_fb = ws + 6400000;             // fallback-only f32 h1 (overlaps xb/h1b)
    float* S   = ws + 12800000;              // 512 floats: stats & bn params
    float* gsum1  = S;        // 64
    float* gsq1   = S + 64;   // 64
    float* gsum2  = S + 128;  // 2
    float* gsq2   = S + 160;  // 2
    float* scale1 = S + 192;  // 64
    float* shift1 = S + 256;  // 64
    float* scale2 = S + 320;  // 2
    float* shift2 = S + 328;  // 2

    int* ibase  = (int*)(S + 512);
    int* rowptr = ibase;                  // NN+1 (padded to 100004)
    int* csr    = ibase + 100004;         // E
    int* gcnt   = ibase + 100004 + E;     // NB
    int* bbase  = gcnt + 392;             // NB+1
    int* bcur   = bbase + 396;            // NB
    int* part   = (int*)agg;              // E ints, aliased with agg (used before agg)

    size_t needed = (size_t)(12800000 + 512) * 4 + (size_t)(100004 + E + 392 + 396 + 396) * 4;

    const int n4 = NN * FD / 4;
    const int np1 = (E + P1CH - 1) / P1CH;

    if (ws_size >= needed) {
        // ---- bucket-partitioned CSR path + bf16 gathers ----
        k_zero2<<<2, 256, 0, stream>>>(gcnt, NB, S, 192);
        k_cvt<<<2048, 256, 0, stream>>>((const float4*)x, (ushort4*)xb, n4);
        k_p1a<<<np1, 256, 0, stream>>>(ei, gcnt, E);
        k_p1scan<<<1, 512, 0, stream>>>(gcnt, bbase, bcur);
        k_p1b<<<np1, 256, 0, stream>>>(ei, bcur, part, E);
        k_build<<<NB, 256, 0, stream>>>(part, bbase, rowptr, csr, E);

        // conv1: agg = x + gather(x)   (agg overwrites part — part no longer needed)
        k_gather_bf<<<25000, 256, 0, stream>>>(xb, rowptr, csr, nullptr, nullptr, agg, E);
        // conv1 MLP -> h1b (bf16) (+ BN1 stats from exact f32)
        k_mlp64<true><<<(NN + 255) / 256, 256, 0, stream>>>(agg, W1a, b1a, W1b, b1b,
                                                            (void*)h1b, gsum1, gsq1);
        k_bnfin<<<1, 64, 0, stream>>>(gsum1, gsq1, g1, be1, scale1, shift1, 64, 1.f / NN);
        // conv5: agg = bn(h1) + gather(bn(h1))  [affine folded into epilogue]
        k_gather_bf<<<25000, 256, 0, stream>>>(h1b, rowptr, csr, scale1, shift1, agg, E);
        // conv5 MLP -> out (+ BN2 stats)
        k_mlp_out<<<(NN + 255) / 256, 256, 0, stream>>>(agg, W5a, b5a, W5b, b5b, out, gsum2, gsq2);
        k_bnfin<<<1, 64, 0, stream>>>(gsum2, gsq2, g5, be5, scale2, shift2, OUTF, 1.f / NN);
        k_bn_apply2<<<(NN * OUTF + 255) / 256, 256, 0, stream>>>(out, scale2, shift2, NN * OUTF);
    } else {
        // ---- fallback: round-1 atomic path (f32 throughout) ----
        k_zero<<<1, 256, 0, stream>>>(S, 192);
        k_copy4<<<4096, 256, 0, stream>>>((const float4*)x, (float4*)agg, n4);
        k_scatter<<<4096, 256, 0, stream>>>(x, ei, agg, E);
        k_mlp64<false><<<(NN + 255) / 256, 256, 0, stream>>>(agg, W1a, b1a, W1b, b1b,
                                                             (void*)h1_fb, gsum1, gsq1);
        k_bnfin<<<1, 64, 0, stream>>>(gsum1, gsq1, g1, be1, scale1, shift1, 64, 1.f / NN);
        k_bn_copy<<<4096, 256, 0, stream>>>((const float4*)h1_fb, (const float4*)scale1,
                                            (const float4*)shift1, (float4*)agg, n4);
        k_scatter_bn<<<4096, 256, 0, stream>>>(h1_fb, ei, scale1, shift1, agg, E);
        k_mlp_out<<<(NN + 255) / 256, 256, 0, stream>>>(agg, W5a, b5a, W5b, b5b, out, gsum2, gsq2);
        k_bnfin<<<1, 64, 0, stream>>>(gsum2, gsq2, g5, be5, scale2, shift2, OUTF, 1.f / NN);
        k_bn_apply2<<<(NN * OUTF + 255) / 256, 256, 0, stream>>>(out, scale2, shift2, NN * OUTF);
    }
}